// Round 10
// baseline (117.623 us; speedup 1.0000x reference)
//
#include <hip/hip_runtime.h>
#include <hip/hip_bf16.h>

#define THRESH 0.05f
constexpr int B_   = 32;
constexpr int CIN  = 128;
constexpr int COUT = 256;
constexpr int HH   = 56;
constexpr int WW   = 56;
constexpr int HWSZ = HH * WW;            // 3136
constexpr int WELEM = COUT * CIN * 9;    // 294912
constexpr int PADW = 58;                 // padded spatial dim

typedef unsigned short u16;
typedef unsigned long long u64;
typedef __attribute__((ext_vector_type(4))) float  f32x4;
typedef __attribute__((ext_vector_type(8))) short  s16x8;
typedef __attribute__((ext_vector_type(4))) int    i32x4;

typedef const __attribute__((address_space(1))) void* gas1;
typedef __attribute__((address_space(3))) void* las3;
typedef const __attribute__((address_space(3))) void* lcv;
#define GLOAD16(gsrc, ldst) \
    __builtin_amdgcn_global_load_lds((gas1)(gsrc), (las3)(ldst), 16, 0, 0)

// opaque asm ops: compiler cannot sink/fold/remat; waits are manual
#define DSR(dst, base, byteoff) \
    asm volatile("ds_read_b128 %0, %1 offset:%2" : "=v"(dst) : "v"(base), "i"(byteoff))
#define AL(dst, addr, byteoff) \
    asm volatile("global_load_dwordx4 %0, %1, off offset:%2" \
                 : "=v"(dst) : "v"(addr), "i"(byteoff))
#define WVL(vm, lg) \
    asm volatile("s_waitcnt vmcnt(%0) lgkmcnt(%1)" :: "i"(vm), "i"(lg) : "memory")

static __device__ __forceinline__ u16 f2bf(float f) {
    __hip_bfloat16 h = __float2bfloat16(f);
    return *reinterpret_cast<u16*>(&h);
}
static __device__ __forceinline__ s16x8 as_h(i32x4 v) {
    s16x8 r; __builtin_memcpy(&r, &v, 16); return r;
}

// ---------------------------------------------------------------------------
// Kernel 1: per-block maxabs partials
// ---------------------------------------------------------------------------
__global__ __launch_bounds__(256) void maxabs_part(const float* __restrict__ w,
                                                   float* __restrict__ partial) {
    int tid = threadIdx.x;
    float m = 0.0f;
    for (int i = blockIdx.x * 256 + tid; i < WELEM; i += 256 * 256)
        m = fmaxf(m, fabsf(w[i]));
    #pragma unroll
    for (int off = 32; off > 0; off >>= 1) m = fmaxf(m, __shfl_xor(m, off));
    __shared__ float s[4];
    if ((tid & 63) == 0) s[tid >> 6] = m;
    __syncthreads();
    if (tid == 0) partial[blockIdx.x] = fmaxf(fmaxf(s[0], s[1]), fmaxf(s[2], s[3]));
}

// ---------------------------------------------------------------------------
// Kernel 2: reduce + faithful ternary quantize + pack bf16 (PLAIN layout now —
// A is consumed by direct per-lane global loads, no LDS, no XOR swizzle):
// Apack u16 index: ((cc*4 + cot)*64 + row)*288 + tap*32 + (ci&31)
// ---------------------------------------------------------------------------
__global__ __launch_bounds__(256) void quant_pack(const float* __restrict__ w,
                                                  const float* __restrict__ partial,
                                                  const float* __restrict__ Wn,
                                                  u16* __restrict__ Apack) {
    int tid = threadIdx.x;
    float m = partial[tid];
    #pragma unroll
    for (int off = 32; off > 0; off >>= 1) m = fmaxf(m, __shfl_xor(m, off));
    __shared__ float s[4];
    if ((tid & 63) == 0) s[tid >> 6] = m;
    __syncthreads();
    const float mx = fmaxf(fmaxf(s[0], s[1]), fmaxf(s[2], s[3]));
    const float wn = Wn[0];

    int idx = blockIdx.x * 256 + tid;          // ((co*128+ci)*9+tap)
    float nw = w[idx] / mx;
    float q  = (nw > -THRESH && nw <= THRESH) ? 0.0f : nw;
    if (q >  THRESH) q =  1.0f;
    if (q < -THRESH) q = -1.0f;
    if (q == -1.0f)  q = wn;

    int tap = idx % 9;
    int r   = idx / 9;
    int ci  = r % CIN;
    int co  = r / CIN;
    int cc  = ci >> 5, lci = ci & 31;
    int cot = co >> 6, row = co & 63;
    Apack[(size_t)((cc * 4 + cot) * 64 + row) * 288 + tap * 32 + lci] = f2bf(q);
}

// ---------------------------------------------------------------------------
// Kernel 3: X (NCHW f32) -> padded Xt[n][1+h][1+w][ci] bf16 via LDS transpose.
// Blocks with pt==0 additionally zero the padded borders for their image.
// ---------------------------------------------------------------------------
__global__ __launch_bounds__(256) void x_to_bf16t(const float* __restrict__ X,
                                                  u16* __restrict__ XtP) {
    __shared__ u16 T[64 * 136];
    const int b  = blockIdx.x;
    const int n  = b / 49, pt = b - n * 49;
    const int p0 = pt * 64;
    const int tid = threadIdx.x;
    const int ci  = tid >> 1, h2 = tid & 1;

    if (pt == 0) {
        for (int idx = tid; idx < 3648; idx += 256) {
            int c16 = idx & 15, s = idx >> 4;
            int r, c;
            if      (s < 58)  { r = 0;           c = s; }
            else if (s < 116) { r = 57;          c = s - 58; }
            else if (s < 172) { r = s - 116 + 1; c = 0; }
            else              { r = s - 172 + 1; c = 57; }
            size_t site = (size_t)(n * PADW + r) * PADW + c;
            *(s16x8*)(XtP + site * 128 + c16 * 8) = (s16x8){0,0,0,0,0,0,0,0};
        }
    }

    const float* src = X + ((size_t)(n * CIN + ci)) * HWSZ + p0 + h2 * 32;
    #pragma unroll
    for (int j = 0; j < 8; ++j) {
        f32x4 v = *(const f32x4*)(src + j * 4);
        #pragma unroll
        for (int mth = 0; mth < 4; ++mth)
            T[(h2 * 32 + j * 4 + mth) * 136 + ci] = f2bf(v[mth]);
    }
    __syncthreads();
    #pragma unroll
    for (int k = 0; k < 4; ++k) {
        int idx = tid + k * 256;
        int p = idx >> 4, c8 = idx & 15;
        int gp = p0 + p;
        int h = gp / 56, w = gp - h * 56;
        size_t site = (size_t)(n * PADW + 1 + h) * PADW + 1 + w;
        *(s16x8*)(XtP + site * 128 + c8 * 8) = *(const s16x8*)&T[p * 136 + c8 * 8];
    }
}

// ---------------------------------------------------------------------------
// Kernel 4: implicit-GEMM conv. A = direct global->VGPR (opaque asm loads,
// 1-tap-ahead, counted vmcnt; all 8 waves hit the same 4KB/tap slice -> L1).
// B = LDS double-buffer (80 KB), XOR-swizzled, 1-tap-ahead DSR (lgkmcnt(4)).
// In-order vmcnt: "A[t] done" also retires the older B-staging, so staging is
// only forced complete at tap 1-2 (covered). One s_barrier per chunk.
// All 4 chunks fully unrolled (compile-time slots / immediates).
// ---------------------------------------------------------------------------
__global__ __launch_bounds__(512, 2) void conv_mfma(const u16* __restrict__ XtP,
                                                    const u16* __restrict__ Apack,
                                                    float* __restrict__ out) {
    __shared__ u16 Xlds[2][20480];     // 2 x 40,960 B : [640 site][32 ci] linear

    const int tid  = threadIdx.x;
    const int wid  = tid >> 6;
    const int lane = tid & 63;
    const int r16  = lane & 15;
    const int g    = lane >> 4;

    // XCD swizzle: 896 blocks, 112 per XCD -> XCD x owns images 4x..4x+3
    const int bid = blockIdx.x;
    const int s   = (bid & 7) * 112 + (bid >> 3);
    const int n   = s / 28;
    const int rem = s - n * 28;
    const int by  = rem >> 2;
    const int bx  = rem & 3;
    const int co0 = bx * 64;
    const int h0  = by * 8;

    f32x4 acc[4][4];
    #pragma unroll
    for (int i = 0; i < 4; ++i)
        #pragma unroll
        for (int j = 0; j < 4; ++j) acc[i][j] = (f32x4){0.f, 0.f, 0.f, 0.f};

    // ---- B-staging source offsets (u16 units, sans cc term) ----
    const int hbase = n * PADW + h0;
    unsigned int bsrc[5];
    #pragma unroll
    for (int i = 0; i < 5; ++i) {
        int p  = i * 512 + tid;
        int pc = (p < 2320) ? p : (p - 2320);       // clamp tail to valid sites
        int site = pc >> 2, gg = pc & 3;
        int r = site / 58, c = site - r * 58;
        int g2 = gg ^ ((site >> 1) & 3);
        bsrc[i] = (unsigned)(((hbase + r) * PADW + c) * 128 + g2 * 8);
    }

    // ---- B per-tap offsets (BYTES): XOR term invariant in nf ----
    int otapB[9];
    #pragma unroll
    for (int t = 0; t < 9; ++t) {
        int base_t = (wid + t / 3) * 58 + r16 + (t % 3);
        otapB[t] = (base_t * 32 + ((g ^ ((base_t >> 1) & 3)) << 3)) * 2;
    }

    // ---- A per-lane global addresses (bytes), one per mf; +147456B per chunk
    u64 aaddr[4];
    #pragma unroll
    for (int mf = 0; mf < 4; ++mf)
        aaddr[mf] = (u64)(Apack + ((size_t)(bx * 64 + mf * 16 + r16)) * 288 + g * 8);

    i32x4 a[2][4], b[2][4];

    // ---- prologue: stage B chunk0, issue A[0], drain, barrier ----
    {
        #pragma unroll
        for (int i = 0; i < 5; ++i)
            GLOAD16(XtP + (size_t)bsrc[i], &Xlds[0][(i * 512 + wid * 64) * 8]);
        AL(a[0][0], aaddr[0], 0);
        AL(a[0][1], aaddr[1], 0);
        AL(a[0][2], aaddr[2], 0);
        AL(a[0][3], aaddr[3], 0);
        asm volatile("s_waitcnt vmcnt(0)" ::: "memory");
        __builtin_amdgcn_s_barrier();
        __builtin_amdgcn_sched_barrier(0);
    }

#define CHUNK(CC, PAR, LAST)                                                  \
  {                                                                           \
    char* xcur = (char*)&Xlds[(CC) & 1][0];                                   \
    if (!(LAST)) {                                                            \
      _Pragma("unroll")                                                       \
      for (int i = 0; i < 5; ++i)                                             \
        GLOAD16(XtP + (size_t)bsrc[i] + ((CC) + 1) * 32,                      \
                &Xlds[((CC) + 1) & 1][(i * 512 + wid * 64) * 8]);             \
    }                                                                         \
    { lcv xb0 = (lcv)(xcur + otapB[0]);                                       \
      DSR(b[0][0], xb0, 0);    DSR(b[0][1], xb0, 1024);                       \
      DSR(b[0][2], xb0, 2048); DSR(b[0][3], xb0, 3072); }                     \
    __builtin_amdgcn_sched_barrier(0);                                        \
    _Pragma("unroll")                                                         \
    for (int T = 0; T < 9; ++T) {                                             \
      const int ca = (T + (PAR)) & 1, na = ca ^ 1;                            \
      const int cb = T & 1, nb = cb ^ 1;                                      \
      if (T == 8 && !(LAST)) {                                                \
        aaddr[0] += 147456; aaddr[1] += 147456;                               \
        aaddr[2] += 147456; aaddr[3] += 147456;                               \
      }                                                                       \
      if (!((LAST) && T == 8)) {                                              \
        const int aoff = (T < 8) ? (T + 1) * 64 : 0;                          \
        AL(a[na][0], aaddr[0], aoff);                                         \
        AL(a[na][1], aaddr[1], aoff);                                         \
        AL(a[na][2], aaddr[2], aoff);                                         \
        AL(a[na][3], aaddr[3], aoff);                                         \
      }                                                                       \
      if (T < 8) {                                                            \
        lcv xb = (lcv)(xcur + otapB[T + 1]);                                  \
        DSR(b[nb][0], xb, 0);    DSR(b[nb][1], xb, 1024);                     \
        DSR(b[nb][2], xb, 2048); DSR(b[nb][3], xb, 3072);                     \
      }                                                                       \
      WVL((T == 0 ? ((LAST) ? 4 : 9) : (((LAST) && T == 8) ? 0 : 4)),         \
          (T < 8 ? 4 : 0));                                                   \
      __builtin_amdgcn_sched_barrier(0);                                      \
      __builtin_amdgcn_s_setprio(1);                                          \
      _Pragma("unroll")                                                       \
      for (int mf = 0; mf < 4; ++mf)                                          \
        _Pragma("unroll")                                                     \
        for (int nf = 0; nf < 4; ++nf)                                        \
          acc[mf][nf] = __builtin_amdgcn_mfma_f32_16x16x32_bf16(              \
              as_h(a[ca][mf]), as_h(b[cb][nf]), acc[mf][nf], 0, 0, 0);        \
      __builtin_amdgcn_s_setprio(0);                                          \
      __builtin_amdgcn_sched_barrier(0);                                      \
    }                                                                         \
    if (!(LAST)) {                                                            \
      __builtin_amdgcn_s_barrier();                                           \
      __builtin_amdgcn_sched_barrier(0);                                      \
    }                                                                         \
  }

    CHUNK(0, 0, false)
    CHUNK(1, 1, false)
    CHUNK(2, 0, false)
    CHUNK(3, 1, true)
#undef CHUNK

    // ---- store: D col = r16 (spatial), row = g*4+j (co) ----
    const int h = h0 + wid;
    float* obase = out + ((size_t)(n * COUT + co0)) * HWSZ + h * WW;
    #pragma unroll
    for (int mf = 0; mf < 4; ++mf)
        #pragma unroll
        for (int nf = 0; nf < 4; ++nf) {
            int col = nf * 16 + r16;
            if (col < WW) {
                #pragma unroll
                for (int j = 0; j < 4; ++j) {
                    int co = mf * 16 + g * 4 + j;
                    obase[(size_t)co * HWSZ + col] = acc[mf][nf][j];
                }
            }
        }
}

// ---------------------------------------------------------------------------
// Launch
// ---------------------------------------------------------------------------
extern "C" void kernel_launch(void* const* d_in, const int* in_sizes, int n_in,
                              void* d_out, int out_size, void* d_ws, size_t ws_size,
                              hipStream_t stream) {
    const float* X      = (const float*)d_in[0];
    const float* weight = (const float*)d_in[1];
    // Wp (d_in[2]) never enters the forward (faithful to source)
    const float* Wn     = (const float*)d_in[3];
    float* out = (float*)d_out;

    float* ws_partial = (float*)d_ws;                        // 256 f32
    u16*   ws_apack   = (u16*)((char*)d_ws + 4096);          // 294912 u16
    u16*   ws_xtp     = (u16*)((char*)d_ws + (1 << 20));     // 32*3364*128 u16 (~27.5 MB)

    maxabs_part<<<256, 256, 0, stream>>>(weight, ws_partial);
    quant_pack<<<WELEM / 256, 256, 0, stream>>>(weight, ws_partial, Wn, ws_apack);
    x_to_bf16t<<<B_ * (HWSZ / 64), 256, 0, stream>>>(X, ws_xtp);

    conv_mfma<<<896, 512, 0, stream>>>(ws_xtp, ws_apack, out);
}

// Round 11
// 104.573 us; speedup vs baseline: 1.1248x; 1.1248x over previous
//
#include <hip/hip_runtime.h>
#include <hip/hip_bf16.h>

#define THRESH 0.05f
constexpr int B_   = 32;
constexpr int CIN  = 128;
constexpr int COUT = 256;
constexpr int HH   = 56;
constexpr int WW   = 56;
constexpr int HWSZ = HH * WW;            // 3136
constexpr int WELEM = COUT * CIN * 9;    // 294912
constexpr int PADW = 58;                 // padded spatial dim

typedef unsigned short u16;
typedef __attribute__((ext_vector_type(4))) float  f32x4;
typedef __attribute__((ext_vector_type(8))) short  s16x8;
typedef __attribute__((ext_vector_type(4))) int    i32x4;

typedef const __attribute__((address_space(1))) void* gas1;
typedef __attribute__((address_space(3))) void* las3;
typedef const __attribute__((address_space(3))) void* lcv;
#define GLOAD16(gsrc, ldst) \
    __builtin_amdgcn_global_load_lds((gas1)(gsrc), (las3)(ldst), 16, 0, 0)

// opaque LDS vector read: compiler cannot sink/fold/remat
#define DSR(dst, base, byteoff) \
    asm volatile("ds_read_b128 %0, %1 offset:%2" : "=v"(dst) : "v"(base), "i"(byteoff))

static __device__ __forceinline__ u16 f2bf(float f) {
    __hip_bfloat16 h = __float2bfloat16(f);
    return *reinterpret_cast<u16*>(&h);
}
static __device__ __forceinline__ s16x8 as_h(i32x4 v) {
    s16x8 r; __builtin_memcpy(&r, &v, 16); return r;
}

// ---------------------------------------------------------------------------
// Kernel 1: per-block maxabs partials
// ---------------------------------------------------------------------------
__global__ __launch_bounds__(256) void maxabs_part(const float* __restrict__ w,
                                                   float* __restrict__ partial) {
    int tid = threadIdx.x;
    float m = 0.0f;
    for (int i = blockIdx.x * 256 + tid; i < WELEM; i += 256 * 256)
        m = fmaxf(m, fabsf(w[i]));
    #pragma unroll
    for (int off = 32; off > 0; off >>= 1) m = fmaxf(m, __shfl_xor(m, off));
    __shared__ float s[4];
    if ((tid & 63) == 0) s[tid >> 6] = m;
    __syncthreads();
    if (tid == 0) partial[blockIdx.x] = fmaxf(fmaxf(s[0], s[1]), fmaxf(s[2], s[3]));
}

// ---------------------------------------------------------------------------
// Kernel 2: reduce + faithful ternary quantize + pack bf16, PERMUTED for the
// 128-co tile: Apack u16 idx = ((cc*2+cot)*128 + row)*288 + tap*32 + swz*8 + e
//   cot = co>>7, row = co&127, ci = cc*32 + g*8 + e, swz = g ^ ((row>>1)&3)
// ---------------------------------------------------------------------------
__global__ __launch_bounds__(256) void quant_pack(const float* __restrict__ w,
                                                  const float* __restrict__ partial,
                                                  const float* __restrict__ Wn,
                                                  u16* __restrict__ Apack) {
    int tid = threadIdx.x;
    float m = partial[tid];
    #pragma unroll
    for (int off = 32; off > 0; off >>= 1) m = fmaxf(m, __shfl_xor(m, off));
    __shared__ float s[4];
    if ((tid & 63) == 0) s[tid >> 6] = m;
    __syncthreads();
    const float mx = fmaxf(fmaxf(s[0], s[1]), fmaxf(s[2], s[3]));
    const float wn = Wn[0];

    int idx = blockIdx.x * 256 + tid;          // ((co*128+ci)*9+tap)
    float nw = w[idx] / mx;
    float q  = (nw > -THRESH && nw <= THRESH) ? 0.0f : nw;
    if (q >  THRESH) q =  1.0f;
    if (q < -THRESH) q = -1.0f;
    if (q == -1.0f)  q = wn;

    int tap = idx % 9;
    int r   = idx / 9;
    int ci  = r % CIN;
    int co  = r / CIN;
    int cc  = ci >> 5, lci = ci & 31, g = lci >> 3, e = lci & 7;
    int cot = co >> 7, row = co & 127;
    int swz = g ^ ((row >> 1) & 3);
    Apack[(size_t)((cc * 2 + cot) * 128 + row) * 288 + tap * 32 + swz * 8 + e] = f2bf(q);
}

// ---------------------------------------------------------------------------
// Kernel 3: X (NCHW f32) -> padded Xt[n][1+h][1+w][ci] bf16 via LDS transpose.
// Blocks with pt==0 additionally zero the padded borders for their image.
// ---------------------------------------------------------------------------
__global__ __launch_bounds__(256) void x_to_bf16t(const float* __restrict__ X,
                                                  u16* __restrict__ XtP) {
    __shared__ u16 T[64 * 136];
    const int b  = blockIdx.x;
    const int n  = b / 49, pt = b - n * 49;
    const int p0 = pt * 64;
    const int tid = threadIdx.x;
    const int ci  = tid >> 1, h2 = tid & 1;

    if (pt == 0) {
        for (int idx = tid; idx < 3648; idx += 256) {
            int c16 = idx & 15, s = idx >> 4;
            int r, c;
            if      (s < 58)  { r = 0;           c = s; }
            else if (s < 116) { r = 57;          c = s - 58; }
            else if (s < 172) { r = s - 116 + 1; c = 0; }
            else              { r = s - 172 + 1; c = 57; }
            size_t site = (size_t)(n * PADW + r) * PADW + c;
            *(s16x8*)(XtP + site * 128 + c16 * 8) = (s16x8){0,0,0,0,0,0,0,0};
        }
    }

    const float* src = X + ((size_t)(n * CIN + ci)) * HWSZ + p0 + h2 * 32;
    #pragma unroll
    for (int j = 0; j < 8; ++j) {
        f32x4 v = *(const f32x4*)(src + j * 4);
        #pragma unroll
        for (int mth = 0; mth < 4; ++mth)
            T[(h2 * 32 + j * 4 + mth) * 136 + ci] = f2bf(v[mth]);
    }
    __syncthreads();
    #pragma unroll
    for (int k = 0; k < 4; ++k) {
        int idx = tid + k * 256;
        int p = idx >> 4, c8 = idx & 15;
        int gp = p0 + p;
        int h = gp / 56, w = gp - h * 56;
        size_t site = (size_t)(n * PADW + 1 + h) * PADW + 1 + w;
        *(s16x8*)(XtP + site * 128 + c8 * 8) = *(const s16x8*)&T[p * 136 + c8 * 8];
    }
}

// ---------------------------------------------------------------------------
// Kernel 4: implicit-GEMM conv — block 128co x 8rows, wave = 64co x 2rows
// (2x4 wave grid). A: single LDS buffer 72KB, staged once per chunk (after a
// barrier), read via asm ds_read. B: double-buffered 80KB, prefetch-staged.
// Per tap per wave: 12 ds_read_b128 (4 A + 8 B), 32 MFMA — MFMA (1242cy/CU)
// now covers LDS (860cy/CU). 1-tap-lookahead asm pipeline, lgkmcnt(12).
// 448 blocks, 1 blk/CU.
// ---------------------------------------------------------------------------
__global__ __launch_bounds__(512, 2) void conv_mfma(const u16* __restrict__ XtP,
                                                    const u16* __restrict__ Apack,
                                                    float* __restrict__ out) {
    __shared__ u16 Alds[36864];        // 73,728 B : [128 row][288 k] linear
    __shared__ u16 Xlds[2][20480];     // 2 x 40,960 B : [640 site][32 ci] linear

    const int tid  = threadIdx.x;
    const int wid  = tid >> 6;
    const int lane = tid & 63;
    const int r16  = lane & 15;
    const int g    = lane >> 4;
    const int cohalf = wid >> 2;       // 0..1 : which 64-co half
    const int rp     = wid & 3;        // 0..3 : which row-pair

    // XCD swizzle: 448 blocks, 56 per XCD
    const int bid = blockIdx.x;
    const int s   = (bid & 7) * 56 + (bid >> 3);
    const int n   = s / 14;
    const int rem = s - n * 14;
    const int by  = rem >> 1;          // 0..6
    const int bx  = rem & 1;           // 0..1
    const int co0 = bx * 128;
    const int h0  = by * 8;

    f32x4 acc[4][8];
    #pragma unroll
    for (int i = 0; i < 4; ++i)
        #pragma unroll
        for (int j = 0; j < 8; ++j) acc[i][j] = (f32x4){0.f, 0.f, 0.f, 0.f};

    // ---- B-staging source offsets (u16 units, sans cc term) ----
    const int hbase = n * PADW + h0;
    unsigned int bsrc[5];
    #pragma unroll
    for (int i = 0; i < 5; ++i) {
        int p  = i * 512 + tid;
        int pc = (p < 2320) ? p : (p - 2320);       // clamp tail to valid sites
        int site = pc >> 2, gg = pc & 3;
        int r = site / 58, c = site - r * 58;
        int g2 = gg ^ ((site >> 1) & 3);
        bsrc[i] = (unsigned)(((hbase + r) * PADW + c) * 128 + g2 * 8);
    }

    // ---- A fragment LDS base (bytes): swizzle invariant in cohalf/mf/tap ----
    lcv AbL = (lcv)((const char*)&Alds[0] + cohalf * 36864
                    + (r16 * 288 + ((g ^ ((r16 >> 1) & 3)) << 3)) * 2);

    // ---- B per-lane site base: site = rbase + (rr+dh)*58 + dw (imm) ----
    const int rbase = (rp * 2) * 58 + r16;
    const int gsw   = g;               // for inline swizzle

    // B byte-offset from site (inline, ~5 VALU): (site<<6) + ((g^((site>>1)&3))<<4)
#define BOFF(SITE) (((SITE) << 6) + ((gsw ^ (((SITE) >> 1) & 3)) << 4))

    // ---- prologue: stage A[0] + B[0], drain, barrier ----
    {
        const u16* asrc = Apack + (size_t)bx * 36864;
        #pragma unroll
        for (int i = 0; i < 9; ++i)
            GLOAD16(asrc + (size_t)(i * 512 + tid) * 8, &Alds[(i * 512 + wid * 64) * 8]);
        #pragma unroll
        for (int i = 0; i < 5; ++i)
            GLOAD16(XtP + (size_t)bsrc[i], &Xlds[0][(i * 512 + wid * 64) * 8]);
        asm volatile("s_waitcnt vmcnt(0)" ::: "memory");
        __builtin_amdgcn_s_barrier();
        __builtin_amdgcn_sched_barrier(0);
    }

    i32x4 af[2][4], bf[2][8];

#define CHUNK(CC, LAST)                                                       \
  {                                                                           \
    char* xcur = (char*)&Xlds[(CC) & 1][0];                                   \
    if (!(LAST)) {                                                            \
      _Pragma("unroll")                                                       \
      for (int i = 0; i < 5; ++i)                                             \
        GLOAD16(XtP + (size_t)bsrc[i] + ((CC) + 1) * 32,                      \
                &Xlds[((CC) + 1) & 1][(i * 512 + wid * 64) * 8]);             \
    }                                                                         \
    /* preload tap 0 */                                                       \
    {                                                                         \
      DSR(af[0][0], AbL, 0 * 9216); DSR(af[0][1], AbL, 1 * 9216);             \
      DSR(af[0][2], AbL, 2 * 9216); DSR(af[0][3], AbL, 3 * 9216);             \
      _Pragma("unroll")                                                       \
      for (int rr = 0; rr < 2; ++rr) {                                        \
        int site = rbase + rr * 58;                                           \
        lcv xb = (lcv)(xcur + BOFF(site));                                    \
        DSR(bf[0][rr * 4 + 0], xb, 0);    DSR(bf[0][rr * 4 + 1], xb, 1024);   \
        DSR(bf[0][rr * 4 + 2], xb, 2048); DSR(bf[0][rr * 4 + 3], xb, 3072);   \
      }                                                                       \
    }                                                                         \
    __builtin_amdgcn_sched_barrier(0);                                        \
    _Pragma("unroll")                                                         \
    for (int T = 0; T < 9; ++T) {                                             \
      const int cs = T & 1, ns = cs ^ 1;                                      \
      if (T < 8) {                                                            \
        const int tp = T + 1, dh = tp / 3, dw = tp % 3;                       \
        DSR(af[ns][0], AbL, 0 * 9216 + tp * 64);                              \
        DSR(af[ns][1], AbL, 1 * 9216 + tp * 64);                              \
        DSR(af[ns][2], AbL, 2 * 9216 + tp * 64);                              \
        DSR(af[ns][3], AbL, 3 * 9216 + tp * 64);                              \
        _Pragma("unroll")                                                     \
        for (int rr = 0; rr < 2; ++rr) {                                      \
          int site = rbase + (rr + dh) * 58 + dw;                             \
          lcv xb = (lcv)(xcur + BOFF(site));                                  \
          DSR(bf[ns][rr * 4 + 0], xb, 0);  DSR(bf[ns][rr * 4 + 1], xb, 1024); \
          DSR(bf[ns][rr * 4 + 2], xb, 2048); DSR(bf[ns][rr * 4 + 3], xb, 3072);\
        }                                                                     \
        asm volatile("s_waitcnt lgkmcnt(12)" ::: "memory");                   \
      } else {                                                                \
        asm volatile("s_waitcnt lgkmcnt(0)" ::: "memory");                    \
      }                                                                       \
      __builtin_amdgcn_sched_barrier(0);                                      \
      __builtin_amdgcn_s_setprio(1);                                          \
      _Pragma("unroll")                                                       \
      for (int mf = 0; mf < 4; ++mf)                                          \
        _Pragma("unroll")                                                     \
        for (int nf = 0; nf < 8; ++nf)                                        \
          acc[mf][nf] = __builtin_amdgcn_mfma_f32_16x16x32_bf16(              \
              as_h(af[cs][mf]), as_h(bf[cs][nf]), acc[mf][nf], 0, 0, 0);      \
      __builtin_amdgcn_s_setprio(0);                                          \
      __builtin_amdgcn_sched_barrier(0);                                      \
    }                                                                         \
    if (!(LAST)) {                                                            \
      __builtin_amdgcn_s_barrier();   /* all waves done reading Alds */       \
      const u16* asrcN = Apack + (size_t)(((CC) + 1) * 2 + bx) * 36864;       \
      _Pragma("unroll")                                                       \
      for (int i = 0; i < 9; ++i)                                             \
        GLOAD16(asrcN + (size_t)(i * 512 + tid) * 8,                          \
                &Alds[(i * 512 + wid * 64) * 8]);                             \
      asm volatile("s_waitcnt vmcnt(0)" ::: "memory");                        \
      __builtin_amdgcn_s_barrier();                                           \
      __builtin_amdgcn_sched_barrier(0);                                      \
    }                                                                         \
  }

    CHUNK(0, false)
    CHUNK(1, false)
    CHUNK(2, false)
    CHUNK(3, true)
#undef CHUNK
#undef BOFF

    // ---- store: col = (nf&3)*16 + r16, h = h0 + rp*2 + (nf>>2),
    //             co = co0 + cohalf*64 + mf*16 + g*4 + j ----
    #pragma unroll
    for (int mf = 0; mf < 4; ++mf)
        #pragma unroll
        for (int nf = 0; nf < 8; ++nf) {
            int col = (nf & 3) * 16 + r16;
            if (col < WW) {
                int h = h0 + rp * 2 + (nf >> 2);
                float* op = out + ((size_t)(n * COUT + co0 + cohalf * 64 + mf * 16
                                            + g * 4)) * HWSZ + h * WW + col;
                #pragma unroll
                for (int j = 0; j < 4; ++j)
                    op[(size_t)j * HWSZ] = acc[mf][nf][j];
            }
        }
}

// ---------------------------------------------------------------------------
// Launch
// ---------------------------------------------------------------------------
extern "C" void kernel_launch(void* const* d_in, const int* in_sizes, int n_in,
                              void* d_out, int out_size, void* d_ws, size_t ws_size,
                              hipStream_t stream) {
    const float* X      = (const float*)d_in[0];
    const float* weight = (const float*)d_in[1];
    // Wp (d_in[2]) never enters the forward (faithful to source)
    const float* Wn     = (const float*)d_in[3];
    float* out = (float*)d_out;

    float* ws_partial = (float*)d_ws;                        // 256 f32
    u16*   ws_apack   = (u16*)((char*)d_ws + 4096);          // 294912 u16
    u16*   ws_xtp     = (u16*)((char*)d_ws + (1 << 20));     // 32*3364*128 u16 (~27.5 MB)

    maxabs_part<<<256, 256, 0, stream>>>(weight, ws_partial);
    quant_pack<<<WELEM / 256, 256, 0, stream>>>(weight, ws_partial, Wn, ws_apack);
    x_to_bf16t<<<B_ * (HWSZ / 64), 256, 0, stream>>>(X, ws_xtp);

    conv_mfma<<<448, 512, 0, stream>>>(ws_xtp, ws_apack, out);
}

// Round 12
// 99.518 us; speedup vs baseline: 1.1819x; 1.0508x over previous
//
#include <hip/hip_runtime.h>
#include <hip/hip_bf16.h>

#define THRESH 0.05f
constexpr int B_   = 32;
constexpr int CIN  = 128;
constexpr int COUT = 256;
constexpr int HH   = 56;
constexpr int WW   = 56;
constexpr int HWSZ = HH * WW;            // 3136
constexpr int WELEM = COUT * CIN * 9;    // 294912
constexpr int PADW = 58;                 // padded spatial dim

typedef unsigned short u16;
typedef __attribute__((ext_vector_type(4))) float  f32x4;
typedef __attribute__((ext_vector_type(8))) short  s16x8;
typedef __attribute__((ext_vector_type(4))) int    i32x4;

typedef const __attribute__((address_space(1))) void* gas1;
typedef __attribute__((address_space(3))) void* las3;
typedef const __attribute__((address_space(3))) void* lcv;
#define GLOAD16(gsrc, ldst) \
    __builtin_amdgcn_global_load_lds((gas1)(gsrc), (las3)(ldst), 16, 0, 0)

// opaque LDS vector read: compiler cannot sink/fold/remat
#define DSR(dst, base, byteoff) \
    asm volatile("ds_read_b128 %0, %1 offset:%2" : "=v"(dst) : "v"(base), "i"(byteoff))

static __device__ __forceinline__ u16 f2bf(float f) {
    __hip_bfloat16 h = __float2bfloat16(f);
    return *reinterpret_cast<u16*>(&h);
}
static __device__ __forceinline__ s16x8 as_h(i32x4 v) {
    s16x8 r; __builtin_memcpy(&r, &v, 16); return r;
}

// ---- compile-time vmem issue accounting (uniform per wave) ----
constexpr int aRealP(int P) { return (P >= 0 && P <= 29) ? 1 : 0; }             // A loads: phases 0..29
constexpr int bRealP(int P) { return (P >= 0 && (P % 9) < 5 && (P / 9) < 3) ? 1 : 0; }
constexpr int issuesP(int P) { return aRealP(P) + bRealP(P); }
constexpr int newerAt(int P) { return issuesP(P - 2) + issuesP(P - 1) + issuesP(P); }

// ---------------------------------------------------------------------------
// Kernel 1: per-block maxabs partials
// ---------------------------------------------------------------------------
__global__ __launch_bounds__(256) void maxabs_part(const float* __restrict__ w,
                                                   float* __restrict__ partial) {
    int tid = threadIdx.x;
    float m = 0.0f;
    for (int i = blockIdx.x * 256 + tid; i < WELEM; i += 256 * 256)
        m = fmaxf(m, fabsf(w[i]));
    #pragma unroll
    for (int off = 32; off > 0; off >>= 1) m = fmaxf(m, __shfl_xor(m, off));
    __shared__ float s[4];
    if ((tid & 63) == 0) s[tid >> 6] = m;
    __syncthreads();
    if (tid == 0) partial[blockIdx.x] = fmaxf(fmaxf(s[0], s[1]), fmaxf(s[2], s[3]));
}

// ---------------------------------------------------------------------------
// Kernel 2: quantize + pack, SUB-TILED layout (3 taps per sub):
// Apack u16 idx = (((cc*2+cot)*3 + sub)*128 + row)*96 + j*32 + swz*8 + e
//   sub = tap/3, j = tap%3, row = co&127, cot = co>>7,
//   ci = cc*32 + kg*8 + e, swz = kg ^ ((row>>1)&3)
// ---------------------------------------------------------------------------
__global__ __launch_bounds__(256) void quant_pack(const float* __restrict__ w,
                                                  const float* __restrict__ partial,
                                                  const float* __restrict__ Wn,
                                                  u16* __restrict__ Apack) {
    int tid = threadIdx.x;
    float m = partial[tid];
    #pragma unroll
    for (int off = 32; off > 0; off >>= 1) m = fmaxf(m, __shfl_xor(m, off));
    __shared__ float s[4];
    if ((tid & 63) == 0) s[tid >> 6] = m;
    __syncthreads();
    const float mx = fmaxf(fmaxf(s[0], s[1]), fmaxf(s[2], s[3]));
    const float wn = Wn[0];

    int idx = blockIdx.x * 256 + tid;          // ((co*128+ci)*9+tap)
    float nw = w[idx] / mx;
    float q  = (nw > -THRESH && nw <= THRESH) ? 0.0f : nw;
    if (q >  THRESH) q =  1.0f;
    if (q < -THRESH) q = -1.0f;
    if (q == -1.0f)  q = wn;

    int tap = idx % 9;
    int r   = idx / 9;
    int ci  = r % CIN;
    int co  = r / CIN;
    int cc  = ci >> 5, lci = ci & 31, kg = lci >> 3, e = lci & 7;
    int cot = co >> 7, row = co & 127;
    int sub = tap / 3, j = tap % 3;
    int swz = kg ^ ((row >> 1) & 3);
    Apack[((size_t)((cc * 2 + cot) * 3 + sub) * 128 + row) * 96 + j * 32 + swz * 8 + e]
        = f2bf(q);
}

// ---------------------------------------------------------------------------
// Kernel 3: X (NCHW f32) -> padded Xt bf16; pt==0 blocks zero the borders.
// ---------------------------------------------------------------------------
__global__ __launch_bounds__(256) void x_to_bf16t(const float* __restrict__ X,
                                                  u16* __restrict__ XtP) {
    __shared__ u16 T[64 * 136];
    const int b  = blockIdx.x;
    const int n  = b / 49, pt = b - n * 49;
    const int p0 = pt * 64;
    const int tid = threadIdx.x;
    const int ci  = tid >> 1, h2 = tid & 1;

    if (pt == 0) {
        for (int idx = tid; idx < 3648; idx += 256) {
            int c16 = idx & 15, s = idx >> 4;
            int r, c;
            if      (s < 58)  { r = 0;           c = s; }
            else if (s < 116) { r = 57;          c = s - 58; }
            else if (s < 172) { r = s - 116 + 1; c = 0; }
            else              { r = s - 172 + 1; c = 57; }
            size_t site = (size_t)(n * PADW + r) * PADW + c;
            *(s16x8*)(XtP + site * 128 + c16 * 8) = (s16x8){0,0,0,0,0,0,0,0};
        }
    }

    const float* src = X + ((size_t)(n * CIN + ci)) * HWSZ + p0 + h2 * 32;
    #pragma unroll
    for (int j = 0; j < 8; ++j) {
        f32x4 v = *(const f32x4*)(src + j * 4);
        #pragma unroll
        for (int mth = 0; mth < 4; ++mth)
            T[(h2 * 32 + j * 4 + mth) * 136 + ci] = f2bf(v[mth]);
    }
    __syncthreads();
    #pragma unroll
    for (int k = 0; k < 4; ++k) {
        int idx = tid + k * 256;
        int p = idx >> 4, c8 = idx & 15;
        int gp = p0 + p;
        int h = gp / 56, w = gp - h * 56;
        size_t site = (size_t)(n * PADW + 1 + h) * PADW + 1 + w;
        *(s16x8*)(XtP + site * 128 + c8 * 8) = *(const s16x8*)&T[p * 136 + c8 * 8];
    }
}

// ---------------------------------------------------------------------------
// Kernel 4: conv — m201-style 36-phase pipeline. Tile 128co x 8rows, 512 thr
// (8 waves, wave = 64co x 2rows). A: triple-buffered 3-tap subs (3x24KB),
// staged 2 subs ahead (1 load/thread/phase). B: double-buffered (2x40KB),
// chunk c+1 staged at phases 0-4 of chunk c. Per phase: {stage issues ->
// [vmcnt(newer) if new-sub phase] -> barrier -> 12 DSR lookahead (tap t+1) ->
// lgkmcnt(12) -> setprio 32 MFMA -> barrier}. vmcnt NEVER drains mid-loop.
// ---------------------------------------------------------------------------
struct ConvCtx {
    const u16* XtP; const u16* Apack;
    u16* Asub; u16* Xlds;
    const unsigned int* bsrc;
    int bx, tid, wid;
    lcv abL;                 // A read base (incl. cohalf + r16 + swz)
    const char* xlB;         // &Xlds[0] as bytes
    int rbase, kg;
};

template<int CC, int T>
__device__ __forceinline__ void phase(const ConvCtx& c,
                                      i32x4 (&af)[2][4], i32x4 (&bf)[2][8],
                                      f32x4 (&acc)[4][8]) {
    constexpr int P = CC * 9 + T;
    // ---- stage A (sub g = (P+6)/3, slice j) ----
    {
        constexpr int gA = (P + 6) / 3, jA = (P + 6) % 3;
        if constexpr (gA <= 11) {
            constexpr int scc = gA / 3, ss = gA % 3, bufA = gA % 3;
            GLOAD16(c.Apack + ((size_t)(scc * 6 + ss) + (size_t)c.bx * 3) * 12288
                        + (size_t)(jA * 512 + c.tid) * 8,
                    &c.Asub[bufA * 12288 + (jA * 512 + c.wid * 64) * 8]);
        }
    }
    // ---- stage B (chunk CC+1 slice T, phases 0-4) ----
    {
        if constexpr (bRealP(P)) {
            constexpr int cc1 = P / 9 + 1, tt = P % 9;
            GLOAD16(c.XtP + (size_t)c.bsrc[tt] + cc1 * 32,
                    &c.Xlds[(cc1 & 1) * 20480 + (tt * 512 + c.wid * 64) * 8]);
        }
    }
    // ---- counted vmcnt before DSRs that touch a freshly-staged region ----
    if constexpr (T % 3 == 2)
        asm volatile("s_waitcnt vmcnt(%0)" :: "i"(newerAt(P)) : "memory");
    __builtin_amdgcn_s_barrier();

    // ---- lookahead DSRs for tap P+1 ----
    constexpr bool LASTPH = (CC == 3 && T == 8);
    if constexpr (!LASTPH) {
        constexpr int GT = P + 1;
        constexpr int ns = GT & 1;
        constexpr int gS = GT / 3, bufA = gS % 3, jj = GT % 3;
        constexpr int CG = GT / 9, tt = GT % 9, dh = tt / 3, dw = tt % 3;
        DSR(af[ns][0], c.abL, bufA * 24576 + 0 * 3072 + jj * 64);
        DSR(af[ns][1], c.abL, bufA * 24576 + 1 * 3072 + jj * 64);
        DSR(af[ns][2], c.abL, bufA * 24576 + 2 * 3072 + jj * 64);
        DSR(af[ns][3], c.abL, bufA * 24576 + 3 * 3072 + jj * 64);
        int s0 = c.rbase + dh * 58 + dw;
        int o0 = (s0 << 6) + ((c.kg ^ ((s0 >> 1) & 3)) << 4);
        lcv xb0 = (lcv)(c.xlB + o0);
        DSR(bf[ns][0], xb0, (CG & 1) * 40960 + 0 * 1024);
        DSR(bf[ns][1], xb0, (CG & 1) * 40960 + 1 * 1024);
        DSR(bf[ns][2], xb0, (CG & 1) * 40960 + 2 * 1024);
        DSR(bf[ns][3], xb0, (CG & 1) * 40960 + 3 * 1024);
        int s1 = s0 + 58;
        int o1 = (s1 << 6) + ((c.kg ^ ((s1 >> 1) & 3)) << 4);
        lcv xb1 = (lcv)(c.xlB + o1);
        DSR(bf[ns][4], xb1, (CG & 1) * 40960 + 0 * 1024);
        DSR(bf[ns][5], xb1, (CG & 1) * 40960 + 1 * 1024);
        DSR(bf[ns][6], xb1, (CG & 1) * 40960 + 2 * 1024);
        DSR(bf[ns][7], xb1, (CG & 1) * 40960 + 3 * 1024);
    }
    asm volatile("s_waitcnt lgkmcnt(%0)" :: "i"(LASTPH ? 0 : 12) : "memory");
    __builtin_amdgcn_sched_barrier(0);
    __builtin_amdgcn_s_setprio(1);
    constexpr int cs = P & 1;
    #pragma unroll
    for (int mf = 0; mf < 4; ++mf)
        #pragma unroll
        for (int nf = 0; nf < 8; ++nf)
            acc[mf][nf] = __builtin_amdgcn_mfma_f32_16x16x32_bf16(
                as_h(af[cs][mf]), as_h(bf[cs][nf]), acc[mf][nf], 0, 0, 0);
    __builtin_amdgcn_s_setprio(0);
    __builtin_amdgcn_sched_barrier(0);
    __builtin_amdgcn_s_barrier();
}

__global__ __launch_bounds__(512, 2) void conv_mfma(const u16* __restrict__ XtP,
                                                    const u16* __restrict__ Apack,
                                                    float* __restrict__ out) {
    __shared__ u16 Asub[3 * 12288];    // 3 x 24,576 B : [128 row][96 u16] subs
    __shared__ u16 Xlds[2 * 20480];    // 2 x 40,960 B : [640 site][32 ci]

    const int tid  = threadIdx.x;
    const int wid  = tid >> 6;
    const int lane = tid & 63;
    const int r16  = lane & 15;
    const int kg   = lane >> 4;
    const int cohalf = wid >> 2;
    const int rp     = wid & 3;

    // XCD swizzle: 448 blocks, 56 per XCD
    const int bid = blockIdx.x;
    const int s   = (bid & 7) * 56 + (bid >> 3);
    const int n   = s / 14;
    const int rem = s - n * 14;
    const int by  = rem >> 1;
    const int bx  = rem & 1;
    const int co0 = bx * 128;
    const int h0  = by * 8;

    f32x4 acc[4][8];
    #pragma unroll
    for (int i = 0; i < 4; ++i)
        #pragma unroll
        for (int j = 0; j < 8; ++j) acc[i][j] = (f32x4){0.f, 0.f, 0.f, 0.f};

    // ---- B-staging source offsets (u16 units, sans cc term) ----
    const int hbase = n * PADW + h0;
    unsigned int bsrc[5];
    #pragma unroll
    for (int i = 0; i < 5; ++i) {
        int p  = i * 512 + tid;
        int pc = (p < 2320) ? p : (p - 2320);
        int site = pc >> 2, gg = pc & 3;
        int r = site / 58, cl = site - r * 58;
        int g2 = gg ^ ((site >> 1) & 3);
        bsrc[i] = (unsigned)(((hbase + r) * PADW + cl) * 128 + g2 * 8);
    }

    // ---- A read base: cohalf + row(r16) + swz, buffer/mf/tap via immediates
    const int swzA = kg ^ ((r16 >> 1) & 3);
    lcv abL = (lcv)((const char*)&Asub[0] + cohalf * 12288 + r16 * 192 + swzA * 16);
    const char* xlB = (const char*)&Xlds[0];
    const int rbase = (rp * 2) * 58 + r16;

    i32x4 af[2][4], bf[2][8];

    // ---- prologue: stage sub0+sub1 (A) + chunk0 (B); drain; preload tap0 ----
    {
        #pragma unroll
        for (int gg = 0; gg < 2; ++gg)
            #pragma unroll
            for (int j = 0; j < 3; ++j)
                GLOAD16(Apack + ((size_t)(bx * 3 + gg)) * 12288 + (size_t)(j * 512 + tid) * 8,
                        &Asub[gg * 12288 + (j * 512 + wid * 64) * 8]);
        #pragma unroll
        for (int i = 0; i < 5; ++i)
            GLOAD16(XtP + (size_t)bsrc[i], &Xlds[(i * 512 + wid * 64) * 8]);
        asm volatile("s_waitcnt vmcnt(0)" ::: "memory");
        __builtin_amdgcn_s_barrier();
        __builtin_amdgcn_sched_barrier(0);
        // preload tap0 (GT=0): set0, sub0/buf0, j=0, B chunk0/buf0, dh=dw=0
        DSR(af[0][0], abL, 0 * 3072);
        DSR(af[0][1], abL, 1 * 3072);
        DSR(af[0][2], abL, 2 * 3072);
        DSR(af[0][3], abL, 3 * 3072);
        int s0 = rbase;
        int o0 = (s0 << 6) + ((kg ^ ((s0 >> 1) & 3)) << 4);
        lcv xb0 = (lcv)(xlB + o0);
        DSR(bf[0][0], xb0, 0);    DSR(bf[0][1], xb0, 1024);
        DSR(bf[0][2], xb0, 2048); DSR(bf[0][3], xb0, 3072);
        int s1 = s0 + 58;
        int o1 = (s1 << 6) + ((kg ^ ((s1 >> 1) & 3)) << 4);
        lcv xb1 = (lcv)(xlB + o1);
        DSR(bf[0][4], xb1, 0);    DSR(bf[0][5], xb1, 1024);
        DSR(bf[0][6], xb1, 2048); DSR(bf[0][7], xb1, 3072);
    }

    ConvCtx ctx{XtP, Apack, Asub, Xlds, bsrc, bx, tid, wid, abL, xlB, rbase, kg};

    phase<0,0>(ctx, af, bf, acc); phase<0,1>(ctx, af, bf, acc); phase<0,2>(ctx, af, bf, acc);
    phase<0,3>(ctx, af, bf, acc); phase<0,4>(ctx, af, bf, acc); phase<0,5>(ctx, af, bf, acc);
    phase<0,6>(ctx, af, bf, acc); phase<0,7>(ctx, af, bf, acc); phase<0,8>(ctx, af, bf, acc);
    phase<1,0>(ctx, af, bf, acc); phase<1,1>(ctx, af, bf, acc); phase<1,2>(ctx, af, bf, acc);
    phase<1,3>(ctx, af, bf, acc); phase<1,4>(ctx, af, bf, acc); phase<1,5>(ctx, af, bf, acc);
    phase<1,6>(ctx, af, bf, acc); phase<1,7>(ctx, af, bf, acc); phase<1,8>(ctx, af, bf, acc);
    phase<2,0>(ctx, af, bf, acc); phase<2,1>(ctx, af, bf, acc); phase<2,2>(ctx, af, bf, acc);
    phase<2,3>(ctx, af, bf, acc); phase<2,4>(ctx, af, bf, acc); phase<2,5>(ctx, af, bf, acc);
    phase<2,6>(ctx, af, bf, acc); phase<2,7>(ctx, af, bf, acc); phase<2,8>(ctx, af, bf, acc);
    phase<3,0>(ctx, af, bf, acc); phase<3,1>(ctx, af, bf, acc); phase<3,2>(ctx, af, bf, acc);
    phase<3,3>(ctx, af, bf, acc); phase<3,4>(ctx, af, bf, acc); phase<3,5>(ctx, af, bf, acc);
    phase<3,6>(ctx, af, bf, acc); phase<3,7>(ctx, af, bf, acc); phase<3,8>(ctx, af, bf, acc);

    // ---- store: col = (nf&3)*16 + r16, h = h0 + rp*2 + (nf>>2),
    //             co = co0 + cohalf*64 + mf*16 + kg*4 + j ----
    #pragma unroll
    for (int mf = 0; mf < 4; ++mf)
        #pragma unroll
        for (int nf = 0; nf < 8; ++nf) {
            int col = (nf & 3) * 16 + r16;
            if (col < WW) {
                int h = h0 + rp * 2 + (nf >> 2);
                float* op = out + ((size_t)(n * COUT + co0 + cohalf * 64 + mf * 16
                                            + kg * 4)) * HWSZ + h * WW + col;
                #pragma unroll
                for (int j = 0; j < 4; ++j)
                    op[(size_t)j * HWSZ] = acc[mf][nf][j];
            }
        }
}

// ---------------------------------------------------------------------------
// Launch
// ---------------------------------------------------------------------------
extern "C" void kernel_launch(void* const* d_in, const int* in_sizes, int n_in,
                              void* d_out, int out_size, void* d_ws, size_t ws_size,
                              hipStream_t stream) {
    const float* X      = (const float*)d_in[0];
    const float* weight = (const float*)d_in[1];
    // Wp (d_in[2]) never enters the forward (faithful to source)
    const float* Wn     = (const float*)d_in[3];
    float* out = (float*)d_out;

    float* ws_partial = (float*)d_ws;                        // 256 f32
    u16*   ws_apack   = (u16*)((char*)d_ws + 4096);          // 294912 u16
    u16*   ws_xtp     = (u16*)((char*)d_ws + (1 << 20));     // 32*3364*128 u16 (~27.5 MB)

    maxabs_part<<<256, 256, 0, stream>>>(weight, ws_partial);
    quant_pack<<<WELEM / 256, 256, 0, stream>>>(weight, ws_partial, Wn, ws_apack);
    x_to_bf16t<<<B_ * (HWSZ / 64), 256, 0, stream>>>(X, ws_xtp);

    conv_mfma<<<448, 512, 0, stream>>>(ws_xtp, ws_apack, out);
}